// Round 22
// baseline (127.386 us; speedup 1.0000x reference)
//
#include <hip/hip_runtime.h>
#include <hip/hip_bf16.h>

#define LRELU(v) ((v) > 0.0f ? (v) : 0.2f * (v))
#define PPARTS 32
#define LCAP 4096
#define BCAP 4096   // fixed capacity per dst-bucket (mean fill ~2686, sigma ~51)

typedef float f32x2 __attribute__((ext_vector_type(2)));

__device__ __forceinline__ unsigned short f2bf(float f) {
    unsigned int u = __float_as_uint(f);
    unsigned int r = (u >> 16) & 1;
    u += 0x7fff + r;                 // round-to-nearest-even
    return (unsigned short)(u >> 16);
}
__device__ __forceinline__ float bf2f(unsigned short s) {
    return __uint_as_float(((unsigned int)s) << 16);
}
__device__ __forceinline__ float2 fma2(float2 a, float2 b, float2 c) {
    return make_float2(fmaf(a.x, b.x, c.x), fmaf(a.y, b.y, c.y));
}

// ---------------- init: zero bucket cursors + layer-1 dot constants ----------------
__global__ void k_init(int* __restrict__ cursor, int nb,
                       const float* __restrict__ W1, const float* __restrict__ a1s,
                       const float* __restrict__ a1d, float* __restrict__ dots) {
    int t = threadIdx.x;            // 1024 threads
    if (t < 128) {
        float w = W1[t];
        float ps = w * a1s[t];
        float pd = w * a1d[t];
        #pragma unroll
        for (int o = 16; o; o >>= 1) {
            ps += __shfl_xor(ps, o, 32);
            pd += __shfl_xor(pd, o, 32);
        }
        if ((t & 31) == 0) {
            dots[t >> 5] = ps;
            dots[4 + (t >> 5)] = pd;
        }
    }
    if (t < nb) cursor[t] = 0;
}

// ---------------- bucket scatter with LDS counting sort (sorted global writes) ----------------
__global__ void k_scat(const int* __restrict__ ei, int* __restrict__ cursor,
                       int* __restrict__ pairbuf, int E, int N, int nb) {
    __shared__ int h[1024];
    __shared__ int loff[1024];
    __shared__ int basearr[1024];
    __shared__ int lpair[8192];
    __shared__ unsigned short lbid[8192];
    __shared__ int wsum[16];
    int t = threadIdx.x;            // 1024 threads
    h[t] = 0;
    __syncthreads();
    int ET = E + N;
    int base = blockIdx.x * 8192;
    int end = base + 8192 < ET ? base + 8192 : ET;
    for (int e = base + t; e < end; e += 1024) {
        int d = (e < E) ? ei[E + e] : (e - E);
        atomicAdd(&h[d >> 7], 1);
    }
    __syncthreads();
    int v = h[t];
    int lane = t & 63, w = t >> 6;
    int sv = v;
    #pragma unroll
    for (int o = 1; o < 64; o <<= 1) {
        int u = __shfl_up(sv, o, 64);
        if (lane >= o) sv += u;
    }
    if (lane == 63) wsum[w] = sv;
    __syncthreads();
    if (t < 16) {
        int ws2 = wsum[t];
        #pragma unroll
        for (int o = 1; o < 16; o <<= 1) {
            int u = __shfl_up(ws2, o, 16);
            if (t >= o) ws2 += u;
        }
        wsum[t] = ws2;
    }
    __syncthreads();
    int excl = sv - v + (w ? wsum[w - 1] : 0);
    loff[t] = excl;
    if (t < nb && v) basearr[t] = t * BCAP + atomicAdd(&cursor[t], v);
    __syncthreads();
    h[t] = 0;
    __syncthreads();
    for (int e = base + t; e < end; e += 1024) {
        int s, d;
        if (e < E) { s = ei[e]; d = ei[E + e]; } else { s = d = e - E; }
        int b = d >> 7;
        int lpos = loff[b] + atomicAdd(&h[b], 1);
        lpair[lpos] = (s << 7) | (d & 127);
        lbid[lpos] = (unsigned short)b;
    }
    __syncthreads();
    int total = end - base;
    for (int i = t; i < total; i += 1024) {
        int b = lbid[i];
        pairbuf[basearr[b] + (i - loff[b])] = lpair[i];
    }
}

// ---------------- build (+ fused layer 1): one 512-thread block per bucket ----------------
__global__ void k_build(const int* __restrict__ pairbuf, const int* __restrict__ cursor,
                        int* __restrict__ rowp, int* __restrict__ degarr, int* __restrict__ col,
                        const float* __restrict__ x, const float* __restrict__ dots,
                        float* __restrict__ S, int N) {
    int b = blockIdx.x;
    __shared__ int deg[128];
    __shared__ int inc[128];
    __shared__ int rbase[128];
    __shared__ int cur[128];
    __shared__ int lcol[LCAP];
    int s0 = b * BCAP;
    int cnt = cursor[b];
    int s1 = s0 + cnt;
    bool uselds = (cnt <= LCAP);
    if (threadIdx.x < 128) deg[threadIdx.x] = 0;
    __syncthreads();
    for (int i = s0 + threadIdx.x; i < s1; i += 512)
        atomicAdd(&deg[pairbuf[i] & 127], 1);
    __syncthreads();
    if (threadIdx.x < 128) {
        int lane = threadIdx.x & 63;
        int sv = deg[threadIdx.x];
        #pragma unroll
        for (int o = 1; o < 64; o <<= 1) {
            int u = __shfl_up(sv, o, 64);
            if (lane >= o) sv += u;
        }
        inc[threadIdx.x] = sv;
    }
    __syncthreads();
    if (threadIdx.x < 128) {
        int excl = inc[threadIdx.x] - deg[threadIdx.x] + ((threadIdx.x >= 64) ? inc[63] : 0);
        rbase[threadIdx.x] = s0 + excl;
        cur[threadIdx.x] = 0;
        int node = (b << 7) + threadIdx.x;
        if (node < N) {
            rowp[node] = s0 + excl;
            degarr[node] = deg[threadIdx.x];
        }
    }
    __syncthreads();
    for (int i = s0 + threadIdx.x; i < s1; i += 512) {
        int p = pairbuf[i];
        int off = p & 127;
        int pos = rbase[off] + atomicAdd(&cur[off], 1);
        int srcn = p >> 7;
        col[pos] = srcn;
        if (uselds) lcol[pos - s0] = srcn;
    }
    __syncthreads();

    // fused layer 1: branch-free softmax over incoming edges (32 node-groups x 4 passes)
    float ds0 = dots[0], ds1 = dots[1], ds2 = dots[2], ds3 = dots[3];
    float dd0 = dots[4], dd1 = dots[5], dd2 = dots[6], dd3 = dots[7];
    int lane = threadIdx.x & 15;
    int nl = threadIdx.x >> 4;      // 32 node-groups
    #pragma unroll
    for (int pass = 0; pass < 4; ++pass) {
        int nloc = nl + (pass << 5);
        int node = (b << 7) + nloc;
        if (node >= N) continue;
        int gstart = rbase[nloc];
        int lstart = gstart - s0;
        int dg = deg[nloc];
        float xd = x[node];
        float t0 = xd * dd0, t1 = xd * dd1, t2 = xd * dd2, t3 = xd * dd3;
        float p0 = 0.f, p1 = 0.f, p2 = 0.f, p3 = 0.f;
        float q0 = 0.f, q1 = 0.f, q2 = 0.f, q3 = 0.f;
        for (int i = lane; i < dg; i += 16) {
            int srcn = uselds ? lcol[lstart + i] : col[gstart + i];
            float xs = x[srcn];
            float e0 = LRELU(fmaf(xs, ds0, t0)); float w0 = __expf(e0); p0 += w0; q0 = fmaf(w0, xs, q0);
            float e1 = LRELU(fmaf(xs, ds1, t1)); float w1 = __expf(e1); p1 += w1; q1 = fmaf(w1, xs, q1);
            float e2 = LRELU(fmaf(xs, ds2, t2)); float w2 = __expf(e2); p2 += w2; q2 = fmaf(w2, xs, q2);
            float e3 = LRELU(fmaf(xs, ds3, t3)); float w3 = __expf(e3); p3 += w3; q3 = fmaf(w3, xs, q3);
        }
        #pragma unroll
        for (int o = 8; o; o >>= 1) {
            p0 += __shfl_xor(p0, o, 16); p1 += __shfl_xor(p1, o, 16);
            p2 += __shfl_xor(p2, o, 16); p3 += __shfl_xor(p3, o, 16);
            q0 += __shfl_xor(q0, o, 16); q1 += __shfl_xor(q1, o, 16);
            q2 += __shfl_xor(q2, o, 16); q3 += __shfl_xor(q3, o, 16);
        }
        if (lane == 0) {
            float4 r;
            r.x = q0 / (p0 + 1e-16f);
            r.y = q1 / (p1 + 1e-16f);
            r.z = q2 / (p2 + 1e-16f);
            r.w = q3 / (p3 + 1e-16f);
            *(float4*)(S + node * 4) = r;
        }
    }
}

// ---------------- layer 2 node transform: 2 threads/node (16 channels each) ----------------
__global__ void k_h2(const float* __restrict__ S, const float* __restrict__ W1,
                     const float* __restrict__ b1, const float* __restrict__ W2,
                     const float* __restrict__ a2s, const float* __restrict__ a2d,
                     unsigned int* __restrict__ h2f8, float* __restrict__ es2,
                     float* __restrict__ ed2, int N) {
    __shared__ float sW2[4096];
    __shared__ float sW1[128];
    __shared__ float sb1[128];
    for (int i = threadIdx.x; i < 4096; i += blockDim.x) sW2[i] = W2[i];
    if (threadIdx.x < 128) {
        sW1[threadIdx.x] = W1[threadIdx.x];
        sb1[threadIdx.x] = b1[threadIdx.x];
    }
    __syncthreads();
    int tid = blockIdx.x * blockDim.x + threadIdx.x;
    int n = tid >> 1;
    int half = tid & 1;
    if (n >= N) return;
    float4 sv = *(const float4*)(S + (size_t)n * 4);
    float2 acc2[8];
    #pragma unroll
    for (int c = 0; c < 8; ++c) acc2[c] = make_float2(0.f, 0.f);
    #pragma unroll
    for (int h = 0; h < 4; ++h) {
        float sh = (h == 0) ? sv.x : (h == 1) ? sv.y : (h == 2) ? sv.z : sv.w;
        for (int cc = 0; cc < 32; ++cc) {
            int hc = h * 32 + cc;
            float x1 = fmaf(sh, sW1[hc], sb1[hc]);
            x1 = x1 > 0.f ? x1 : 0.f;
            float2 xv = make_float2(x1, x1);
            const float2* w2row = (const float2*)&sW2[hc * 32 + half * 16];
            #pragma unroll
            for (int c = 0; c < 8; ++c) acc2[c] = fma2(xv, w2row[c], acc2[c]);
        }
    }
    float es = 0.f, edv = 0.f;
    const float* as = a2s + half * 16;
    const float* ad = a2d + half * 16;
    #pragma unroll
    for (int c = 0; c < 8; ++c) {
        es = fmaf(acc2[c].x, as[2 * c], es);
        es = fmaf(acc2[c].y, as[2 * c + 1], es);
        edv = fmaf(acc2[c].x, ad[2 * c], edv);
        edv = fmaf(acc2[c].y, ad[2 * c + 1], edv);
    }
    es += __shfl_xor(es, 1, 64);
    edv += __shfl_xor(edv, 1, 64);
    if (half == 0) { es2[n] = es; ed2[n] = edv; }
    alignas(16) unsigned int hw[4];
    #pragma unroll
    for (int q = 0; q < 4; ++q) {
        int w = __builtin_amdgcn_cvt_pk_fp8_f32(acc2[2 * q].x, acc2[2 * q].y, 0, false);
        w = __builtin_amdgcn_cvt_pk_fp8_f32(acc2[2 * q + 1].x, acc2[2 * q + 1].y, w, true);
        hw[q] = (unsigned int)w;
    }
    *(uint4*)(h2f8 + (size_t)n * 8 + half * 4) = *(const uint4*)hw;
}

// ---------------- layer 2 aggregation: 4 lanes/node = 2 edge-slots x 2 cg (16 ch, uint4) ----------------
__global__ void k_agg(const unsigned int* __restrict__ h2f8, const float* __restrict__ es2,
                      const float* __restrict__ ed2, const int* __restrict__ rowp,
                      const int* __restrict__ degarr, const int* __restrict__ col,
                      const float* __restrict__ b2, unsigned short* __restrict__ x2buf, int N) {
    int gid = blockIdx.x * blockDim.x + threadIdx.x;
    int n = gid >> 2;               // 4 lanes per node (16 nodes per wave)
    int lane = threadIdx.x & 3;
    if (n >= N) return;
    int s = rowp[n];
    int deg = degarr[n];
    float ed = ed2[n];
    int slot = lane >> 1;           // 2 edge slots
    int cg = lane & 1;              // 2 channel-groups of 16 channels
    float sump = 0.f;
    float a[16];
    #pragma unroll
    for (int k = 0; k < 16; ++k) a[k] = 0.f;
    #pragma unroll 2
    for (int j = slot; j < deg; j += 2) {
        int sidx = col[s + j];
        float e = LRELU(es2[sidx] + ed);
        float p = __expf(e);
        sump += p;
        uint4 hv = *(const uint4*)(h2f8 + (size_t)sidx * 8 + cg * 4);
        f32x2 c0 = __builtin_amdgcn_cvt_pk_f32_fp8((int)hv.x, false);
        f32x2 c1 = __builtin_amdgcn_cvt_pk_f32_fp8((int)hv.x, true);
        f32x2 c2 = __builtin_amdgcn_cvt_pk_f32_fp8((int)hv.y, false);
        f32x2 c3 = __builtin_amdgcn_cvt_pk_f32_fp8((int)hv.y, true);
        f32x2 c4 = __builtin_amdgcn_cvt_pk_f32_fp8((int)hv.z, false);
        f32x2 c5 = __builtin_amdgcn_cvt_pk_f32_fp8((int)hv.z, true);
        f32x2 c6 = __builtin_amdgcn_cvt_pk_f32_fp8((int)hv.w, false);
        f32x2 c7 = __builtin_amdgcn_cvt_pk_f32_fp8((int)hv.w, true);
        a[0]  = fmaf(p, c0.x, a[0]);  a[1]  = fmaf(p, c0.y, a[1]);
        a[2]  = fmaf(p, c1.x, a[2]);  a[3]  = fmaf(p, c1.y, a[3]);
        a[4]  = fmaf(p, c2.x, a[4]);  a[5]  = fmaf(p, c2.y, a[5]);
        a[6]  = fmaf(p, c3.x, a[6]);  a[7]  = fmaf(p, c3.y, a[7]);
        a[8]  = fmaf(p, c4.x, a[8]);  a[9]  = fmaf(p, c4.y, a[9]);
        a[10] = fmaf(p, c5.x, a[10]); a[11] = fmaf(p, c5.y, a[11]);
        a[12] = fmaf(p, c6.x, a[12]); a[13] = fmaf(p, c6.y, a[13]);
        a[14] = fmaf(p, c7.x, a[14]); a[15] = fmaf(p, c7.y, a[15]);
    }
    // reduce across the 2 edge-slots (lane bit 1)
    sump += __shfl_xor(sump, 2, 4);
    #pragma unroll
    for (int k = 0; k < 16; ++k) a[k] += __shfl_xor(a[k], 2, 4);
    if (slot == 0) {                // 2 lanes per node, each owns 16 channels
        float inv = 1.0f / (sump + 1e-16f);
        const float* bb = b2 + cg * 16;
        unsigned int w[8];
        #pragma unroll
        for (int q = 0; q < 8; ++q) {
            float t0 = fmaf(a[2 * q], inv, bb[2 * q]);
            t0 = t0 > 0.f ? t0 : 0.f;
            float t1 = fmaf(a[2 * q + 1], inv, bb[2 * q + 1]);
            t1 = t1 > 0.f ? t1 : 0.f;
            w[q] = (unsigned int)f2bf(t0) | ((unsigned int)f2bf(t1) << 16);
        }
        uint4* dst = (uint4*)(x2buf + (size_t)n * 32 + cg * 16);
        dst[0] = make_uint4(w[0], w[1], w[2], w[3]);
        dst[1] = make_uint4(w[4], w[5], w[6], w[7]);
    }
}

// ---------------- pooling stage 1: G*PPARTS blocks, no atomics ----------------
__global__ void k_psum(const unsigned short* __restrict__ x2buf, const int* __restrict__ batch,
                       float* __restrict__ partial, int N) {
    int g = blockIdx.x / PPARTS;
    int part = blockIdx.x % PPARTS;
    __shared__ int sr[2];
    if (threadIdx.x == 0) {
        int lo = 0, hi = N;
        while (lo < hi) { int mid = (lo + hi) >> 1; if (batch[mid] < g) lo = mid + 1; else hi = mid; }
        sr[0] = lo;
        int l2 = lo, h2v = N;
        while (l2 < h2v) { int mid = (l2 + h2v) >> 1; if (batch[mid] < g + 1) l2 = mid + 1; else h2v = mid; }
        sr[1] = l2;
    }
    __syncthreads();
    int lo = sr[0], hi = sr[1];
    int cs = (hi - lo + PPARTS - 1) / PPARTS;
    int start = lo + part * cs;
    int end = start + cs < hi ? start + cs : hi;
    int ch = threadIdx.x & 31;
    int slot = threadIdx.x >> 5;    // 8 node slots
    float acc = 0.f;
    for (int n = start + slot; n < end; n += 8)
        acc += bf2f(x2buf[(size_t)n * 32 + ch]);
    __shared__ float red[256];
    red[threadIdx.x] = acc;
    __syncthreads();
    #pragma unroll
    for (int o = 128; o >= 32; o >>= 1) {
        if (threadIdx.x < o) red[threadIdx.x] += red[threadIdx.x + o];
        __syncthreads();
    }
    if (threadIdx.x < 32)
        partial[(size_t)(g * PPARTS + part) * 32 + threadIdx.x] = red[threadIdx.x];
}

// ---------------- pooling stage 2 + head: one block per graph ----------------
__global__ void k_head(const float* __restrict__ partial, const int* __restrict__ batch,
                       const float* __restrict__ lin_w, const float* __restrict__ lin_b,
                       float* __restrict__ out, int N) {
    int g = blockIdx.x;
    int t = threadIdx.x;            // 64 threads
    int ch = t & 31;
    int half = t >> 5;
    float acc = 0.f;
    for (int p = half * (PPARTS / 2); p < (half + 1) * (PPARTS / 2); ++p)
        acc += partial[(size_t)(g * PPARTS + p) * 32 + ch];
    acc += __shfl_xor(acc, 32, 64);
    int lo = 0, hi = N;
    while (lo < hi) { int mid = (lo + hi) >> 1; if (batch[mid] < g) lo = mid + 1; else hi = mid; }
    int l2 = lo, h2v = N;
    while (l2 < h2v) { int mid = (l2 + h2v) >> 1; if (batch[mid] < g + 1) l2 = mid + 1; else h2v = mid; }
    float c = fmaxf((float)(h2v - lo), 1.0f);
    float v = acc / c * lin_w[ch];
    #pragma unroll
    for (int o = 16; o; o >>= 1) v += __shfl_xor(v, o, 32);
    if (t == 0) out[g] = 1.0f / (1.0f + __expf(-(v + lin_b[0])));
}

extern "C" void kernel_launch(void* const* d_in, const int* in_sizes, int n_in,
                              void* d_out, int out_size, void* d_ws, size_t ws_size,
                              hipStream_t stream) {
    const float* x     = (const float*)d_in[0];
    const int*   ei    = (const int*)d_in[1];
    const int*   batch = (const int*)d_in[2];
    const float* W1    = (const float*)d_in[4];
    const float* a1s   = (const float*)d_in[5];
    const float* a1d   = (const float*)d_in[6];
    const float* b1    = (const float*)d_in[7];
    const float* W2    = (const float*)d_in[8];
    const float* a2s   = (const float*)d_in[9];
    const float* a2d   = (const float*)d_in[10];
    const float* b2    = (const float*)d_in[11];
    const float* lin_w = (const float*)d_in[12];
    const float* lin_b = (const float*)d_in[13];
    float* out = (float*)d_out;

    int N = in_sizes[0];
    int E = in_sizes[1] / 2;
    int ET = E + N;
    int G = out_size;
    int nb = (N + 127) >> 7;        // dst-buckets of 128 nodes
    int nblk = (ET + 8191) / 8192;

    char* ws = (char*)d_ws;
    size_t off = 0;
    auto alloc = [&](size_t bytes) -> char* {
        char* p = ws + off;
        off = (off + bytes + 255) & ~(size_t)255;
        return p;
    };
    int*   cursor  = (int*)alloc(1024 * 4);
    int*   pairbuf = (int*)alloc((size_t)nb * BCAP * 4);
    int*   rowp    = (int*)alloc((size_t)N * 4);
    int*   degarr  = (int*)alloc((size_t)N * 4);
    int*   col     = (int*)alloc((size_t)nb * BCAP * 4);
    float* S       = (float*)alloc((size_t)N * 16);
    unsigned int* h2f8 = (unsigned int*)alloc((size_t)N * 32);
    float* es2     = (float*)alloc((size_t)N * 4);
    float* ed2     = (float*)alloc((size_t)N * 4);
    float* dots    = (float*)alloc(32);
    unsigned short* x2buf = (unsigned short*)alloc((size_t)N * 64);
    float* partial = (float*)alloc((size_t)G * PPARTS * 32 * 4);

    k_init<<<1, 1024, 0, stream>>>(cursor, nb, W1, a1s, a1d, dots);
    k_scat<<<nblk, 1024, 0, stream>>>(ei, cursor, pairbuf, E, N, nb);
    k_build<<<nb, 512, 0, stream>>>(pairbuf, cursor, rowp, degarr, col, x, dots, S, N);
    k_h2<<<((size_t)N * 2 + 255) / 256, 256, 0, stream>>>(S, W1, b1, W2, a2s, a2d, h2f8, es2, ed2, N);
    k_agg<<<((size_t)N * 4 + 255) / 256, 256, 0, stream>>>(h2f8, es2, ed2, rowp, degarr, col, b2, x2buf, N);
    k_psum<<<G * PPARTS, 256, 0, stream>>>(x2buf, batch, partial, N);
    k_head<<<G, 64, 0, stream>>>(partial, batch, lin_w, lin_b, out, N);
}

// Round 23
// 121.572 us; speedup vs baseline: 1.0478x; 1.0478x over previous
//
#include <hip/hip_runtime.h>
#include <hip/hip_bf16.h>

#define LRELU(v) ((v) > 0.0f ? (v) : 0.2f * (v))
#define PPARTS 32
#define LCAP 4096
#define BCAP 4096   // fixed capacity per dst-bucket (mean fill ~2686, sigma ~51)

typedef float f32x2 __attribute__((ext_vector_type(2)));

__device__ __forceinline__ unsigned short f2bf(float f) {
    unsigned int u = __float_as_uint(f);
    unsigned int r = (u >> 16) & 1;
    u += 0x7fff + r;                 // round-to-nearest-even
    return (unsigned short)(u >> 16);
}
__device__ __forceinline__ float bf2f(unsigned short s) {
    return __uint_as_float(((unsigned int)s) << 16);
}
__device__ __forceinline__ float bfl(unsigned int u) {
    return __uint_as_float(u << 16);
}
__device__ __forceinline__ float bfh(unsigned int u) {
    return __uint_as_float(u & 0xffff0000u);
}
__device__ __forceinline__ float2 fma2(float2 a, float2 b, float2 c) {
    return make_float2(fmaf(a.x, b.x, c.x), fmaf(a.y, b.y, c.y));
}

// ---------------- init: zero bucket cursors + layer-1 dot constants ----------------
__global__ void k_init(int* __restrict__ cursor, int nb,
                       const float* __restrict__ W1, const float* __restrict__ a1s,
                       const float* __restrict__ a1d, float* __restrict__ dots) {
    int t = threadIdx.x;            // 1024 threads
    if (t < 128) {
        float w = W1[t];
        float ps = w * a1s[t];
        float pd = w * a1d[t];
        #pragma unroll
        for (int o = 16; o; o >>= 1) {
            ps += __shfl_xor(ps, o, 32);
            pd += __shfl_xor(pd, o, 32);
        }
        if ((t & 31) == 0) {
            dots[t >> 5] = ps;
            dots[4 + (t >> 5)] = pd;
        }
    }
    if (t < nb) cursor[t] = 0;
}

// ---------------- bucket scatter with LDS counting sort (sorted global writes) ----------------
__global__ void k_scat(const int* __restrict__ ei, int* __restrict__ cursor,
                       int* __restrict__ pairbuf, int E, int N, int nb) {
    __shared__ int h[1024];
    __shared__ int loff[1024];
    __shared__ int basearr[1024];
    __shared__ int lpair[8192];
    __shared__ unsigned short lbid[8192];
    __shared__ int wsum[16];
    int t = threadIdx.x;            // 1024 threads
    h[t] = 0;
    __syncthreads();
    int ET = E + N;
    int base = blockIdx.x * 8192;
    int end = base + 8192 < ET ? base + 8192 : ET;
    for (int e = base + t; e < end; e += 1024) {
        int d = (e < E) ? ei[E + e] : (e - E);
        atomicAdd(&h[d >> 7], 1);
    }
    __syncthreads();
    int v = h[t];
    int lane = t & 63, w = t >> 6;
    int sv = v;
    #pragma unroll
    for (int o = 1; o < 64; o <<= 1) {
        int u = __shfl_up(sv, o, 64);
        if (lane >= o) sv += u;
    }
    if (lane == 63) wsum[w] = sv;
    __syncthreads();
    if (t < 16) {
        int ws2 = wsum[t];
        #pragma unroll
        for (int o = 1; o < 16; o <<= 1) {
            int u = __shfl_up(ws2, o, 16);
            if (t >= o) ws2 += u;
        }
        wsum[t] = ws2;
    }
    __syncthreads();
    int excl = sv - v + (w ? wsum[w - 1] : 0);
    loff[t] = excl;
    if (t < nb && v) basearr[t] = t * BCAP + atomicAdd(&cursor[t], v);
    __syncthreads();
    h[t] = 0;
    __syncthreads();
    for (int e = base + t; e < end; e += 1024) {
        int s, d;
        if (e < E) { s = ei[e]; d = ei[E + e]; } else { s = d = e - E; }
        int b = d >> 7;
        int lpos = loff[b] + atomicAdd(&h[b], 1);
        lpair[lpos] = (s << 7) | (d & 127);
        lbid[lpos] = (unsigned short)b;
    }
    __syncthreads();
    int total = end - base;
    for (int i = t; i < total; i += 1024) {
        int b = lbid[i];
        pairbuf[basearr[b] + (i - loff[b])] = lpair[i];
    }
}

// ---------------- build (+ fused layer 1): one 512-thread block per bucket ----------------
__global__ void k_build(const int* __restrict__ pairbuf, const int* __restrict__ cursor,
                        int* __restrict__ rowp, int* __restrict__ degarr, int* __restrict__ col,
                        const float* __restrict__ x, const float* __restrict__ dots,
                        float* __restrict__ S, int N) {
    int b = blockIdx.x;
    __shared__ int deg[128];
    __shared__ int inc[128];
    __shared__ int rbase[128];
    __shared__ int cur[128];
    __shared__ int lcol[LCAP];
    int s0 = b * BCAP;
    int cnt = cursor[b];
    int s1 = s0 + cnt;
    bool uselds = (cnt <= LCAP);
    if (threadIdx.x < 128) deg[threadIdx.x] = 0;
    __syncthreads();
    for (int i = s0 + threadIdx.x; i < s1; i += 512)
        atomicAdd(&deg[pairbuf[i] & 127], 1);
    __syncthreads();
    if (threadIdx.x < 128) {
        int lane = threadIdx.x & 63;
        int sv = deg[threadIdx.x];
        #pragma unroll
        for (int o = 1; o < 64; o <<= 1) {
            int u = __shfl_up(sv, o, 64);
            if (lane >= o) sv += u;
        }
        inc[threadIdx.x] = sv;
    }
    __syncthreads();
    if (threadIdx.x < 128) {
        int excl = inc[threadIdx.x] - deg[threadIdx.x] + ((threadIdx.x >= 64) ? inc[63] : 0);
        rbase[threadIdx.x] = s0 + excl;
        cur[threadIdx.x] = 0;
        int node = (b << 7) + threadIdx.x;
        if (node < N) {
            rowp[node] = s0 + excl;
            degarr[node] = deg[threadIdx.x];
        }
    }
    __syncthreads();
    for (int i = s0 + threadIdx.x; i < s1; i += 512) {
        int p = pairbuf[i];
        int off = p & 127;
        int pos = rbase[off] + atomicAdd(&cur[off], 1);
        int srcn = p >> 7;
        col[pos] = srcn;
        if (uselds) lcol[pos - s0] = srcn;
    }
    __syncthreads();

    // fused layer 1: branch-free softmax over incoming edges (32 node-groups x 4 passes)
    float ds0 = dots[0], ds1 = dots[1], ds2 = dots[2], ds3 = dots[3];
    float dd0 = dots[4], dd1 = dots[5], dd2 = dots[6], dd3 = dots[7];
    int lane = threadIdx.x & 15;
    int nl = threadIdx.x >> 4;      // 32 node-groups
    #pragma unroll
    for (int pass = 0; pass < 4; ++pass) {
        int nloc = nl + (pass << 5);
        int node = (b << 7) + nloc;
        if (node >= N) continue;
        int gstart = rbase[nloc];
        int lstart = gstart - s0;
        int dg = deg[nloc];
        float xd = x[node];
        float t0 = xd * dd0, t1 = xd * dd1, t2 = xd * dd2, t3 = xd * dd3;
        float p0 = 0.f, p1 = 0.f, p2 = 0.f, p3 = 0.f;
        float q0 = 0.f, q1 = 0.f, q2 = 0.f, q3 = 0.f;
        for (int i = lane; i < dg; i += 16) {
            int srcn = uselds ? lcol[lstart + i] : col[gstart + i];
            float xs = x[srcn];
            float e0 = LRELU(fmaf(xs, ds0, t0)); float w0 = __expf(e0); p0 += w0; q0 = fmaf(w0, xs, q0);
            float e1 = LRELU(fmaf(xs, ds1, t1)); float w1 = __expf(e1); p1 += w1; q1 = fmaf(w1, xs, q1);
            float e2 = LRELU(fmaf(xs, ds2, t2)); float w2 = __expf(e2); p2 += w2; q2 = fmaf(w2, xs, q2);
            float e3 = LRELU(fmaf(xs, ds3, t3)); float w3 = __expf(e3); p3 += w3; q3 = fmaf(w3, xs, q3);
        }
        #pragma unroll
        for (int o = 8; o; o >>= 1) {
            p0 += __shfl_xor(p0, o, 16); p1 += __shfl_xor(p1, o, 16);
            p2 += __shfl_xor(p2, o, 16); p3 += __shfl_xor(p3, o, 16);
            q0 += __shfl_xor(q0, o, 16); q1 += __shfl_xor(q1, o, 16);
            q2 += __shfl_xor(q2, o, 16); q3 += __shfl_xor(q3, o, 16);
        }
        if (lane == 0) {
            float4 r;
            r.x = q0 / (p0 + 1e-16f);
            r.y = q1 / (p1 + 1e-16f);
            r.z = q2 / (p2 + 1e-16f);
            r.w = q3 / (p3 + 1e-16f);
            *(float4*)(S + node * 4) = r;
        }
    }
}

// ---------------- layer 2 node transform: float2-packed FMA, h2 as fp8 rows (32 B) ----------------
__global__ void k_h2(const float* __restrict__ S, const float* __restrict__ W1,
                     const float* __restrict__ b1, const float* __restrict__ W2,
                     const float* __restrict__ a2s, const float* __restrict__ a2d,
                     unsigned int* __restrict__ h2f8, float* __restrict__ es2,
                     float* __restrict__ ed2, int N) {
    __shared__ float sW2[4096];
    __shared__ float sW1[128];
    __shared__ float sb1[128];
    for (int i = threadIdx.x; i < 4096; i += blockDim.x) sW2[i] = W2[i];
    if (threadIdx.x < 128) {
        sW1[threadIdx.x] = W1[threadIdx.x];
        sb1[threadIdx.x] = b1[threadIdx.x];
    }
    __syncthreads();
    int n = blockIdx.x * blockDim.x + threadIdx.x;
    if (n >= N) return;
    float4 sv = *(const float4*)(S + (size_t)n * 4);
    float2 acc2[16];
    #pragma unroll
    for (int c = 0; c < 16; ++c) acc2[c] = make_float2(0.f, 0.f);
    #pragma unroll
    for (int h = 0; h < 4; ++h) {
        float sh = (h == 0) ? sv.x : (h == 1) ? sv.y : (h == 2) ? sv.z : sv.w;
        for (int cc = 0; cc < 32; ++cc) {
            int hc = h * 32 + cc;
            float x1 = fmaf(sh, sW1[hc], sb1[hc]);
            x1 = x1 > 0.f ? x1 : 0.f;
            float2 xv = make_float2(x1, x1);
            const float2* w2row = (const float2*)&sW2[hc * 32];
            #pragma unroll
            for (int c = 0; c < 16; ++c) acc2[c] = fma2(xv, w2row[c], acc2[c]);
        }
    }
    float es = 0.f, edv = 0.f;
    #pragma unroll
    for (int c = 0; c < 16; ++c) {
        es = fmaf(acc2[c].x, a2s[2 * c], es);
        es = fmaf(acc2[c].y, a2s[2 * c + 1], es);
        edv = fmaf(acc2[c].x, a2d[2 * c], edv);
        edv = fmaf(acc2[c].y, a2d[2 * c + 1], edv);
    }
    alignas(16) unsigned int hw[8];
    #pragma unroll
    for (int q = 0; q < 8; ++q) {
        int w = __builtin_amdgcn_cvt_pk_fp8_f32(acc2[2 * q].x, acc2[2 * q].y, 0, false);
        w = __builtin_amdgcn_cvt_pk_fp8_f32(acc2[2 * q + 1].x, acc2[2 * q + 1].y, w, true);
        hw[q] = (unsigned int)w;
    }
    uint4* dst = (uint4*)(h2f8 + (size_t)n * 8);
    dst[0] = ((const uint4*)hw)[0];
    dst[1] = ((const uint4*)hw)[1];
    es2[n] = es;
    ed2[n] = edv;
}

// ---------------- layer 2 aggregation: 8 lanes/node = 2 edge-slots x 4 channel-groups ----------------
__global__ void k_agg(const unsigned int* __restrict__ h2f8, const float* __restrict__ es2,
                      const float* __restrict__ ed2, const int* __restrict__ rowp,
                      const int* __restrict__ degarr, const int* __restrict__ col,
                      const float* __restrict__ b2, unsigned short* __restrict__ x2buf, int N) {
    int gid = blockIdx.x * blockDim.x + threadIdx.x;
    int n = gid >> 3;               // 8 lanes per node (8 nodes per wave)
    int lane = threadIdx.x & 7;
    if (n >= N) return;
    int s = rowp[n];
    int deg = degarr[n];
    float ed = ed2[n];
    int slot = lane >> 2;           // 2 edge slots
    int cg = lane & 3;              // 4 channel-groups of 8 channels
    float sump = 0.f;
    float a0 = 0.f, a1 = 0.f, a2 = 0.f, a3 = 0.f, a4 = 0.f, a5 = 0.f, a6 = 0.f, a7 = 0.f;
    #pragma unroll 4
    for (int j = slot; j < deg; j += 2) {
        int sidx = col[s + j];
        float e = LRELU(es2[sidx] + ed);
        float p = __expf(e);
        sump += p;
        uint2 hv = *(const uint2*)(h2f8 + (size_t)sidx * 8 + cg * 2);
        f32x2 c01 = __builtin_amdgcn_cvt_pk_f32_fp8((int)hv.x, false);
        f32x2 c23 = __builtin_amdgcn_cvt_pk_f32_fp8((int)hv.x, true);
        f32x2 c45 = __builtin_amdgcn_cvt_pk_f32_fp8((int)hv.y, false);
        f32x2 c67 = __builtin_amdgcn_cvt_pk_f32_fp8((int)hv.y, true);
        a0 = fmaf(p, c01.x, a0); a1 = fmaf(p, c01.y, a1);
        a2 = fmaf(p, c23.x, a2); a3 = fmaf(p, c23.y, a3);
        a4 = fmaf(p, c45.x, a4); a5 = fmaf(p, c45.y, a5);
        a6 = fmaf(p, c67.x, a6); a7 = fmaf(p, c67.y, a7);
    }
    sump += __shfl_xor(sump, 4, 8);
    a0 += __shfl_xor(a0, 4, 8); a1 += __shfl_xor(a1, 4, 8);
    a2 += __shfl_xor(a2, 4, 8); a3 += __shfl_xor(a3, 4, 8);
    a4 += __shfl_xor(a4, 4, 8); a5 += __shfl_xor(a5, 4, 8);
    a6 += __shfl_xor(a6, 4, 8); a7 += __shfl_xor(a7, 4, 8);
    if (slot == 0) {
        float inv = 1.0f / (sump + 1e-16f);
        const float* bb = b2 + cg * 8;
        float v[8] = {a0, a1, a2, a3, a4, a5, a6, a7};
        unsigned int w[4];
        #pragma unroll
        for (int q = 0; q < 4; ++q) {
            float t0 = fmaf(v[2 * q], inv, bb[2 * q]);
            t0 = t0 > 0.f ? t0 : 0.f;
            float t1 = fmaf(v[2 * q + 1], inv, bb[2 * q + 1]);
            t1 = t1 > 0.f ? t1 : 0.f;
            w[q] = (unsigned int)f2bf(t0) | ((unsigned int)f2bf(t1) << 16);
        }
        uint4* dst = (uint4*)(x2buf + (size_t)n * 32 + cg * 8);
        *dst = make_uint4(w[0], w[1], w[2], w[3]);
    }
}

// ---------------- pooling stage 1: vectorized uint4 loads (8 bf16 ch/lane) ----------------
__global__ void k_psum(const unsigned short* __restrict__ x2buf, const int* __restrict__ batch,
                       float* __restrict__ partial, int N) {
    int g = blockIdx.x / PPARTS;
    int part = blockIdx.x % PPARTS;
    __shared__ int sr[2];
    if (threadIdx.x == 0) {
        int lo = 0, hi = N;
        while (lo < hi) { int mid = (lo + hi) >> 1; if (batch[mid] < g) lo = mid + 1; else hi = mid; }
        sr[0] = lo;
        int l2 = lo, h2v = N;
        while (l2 < h2v) { int mid = (l2 + h2v) >> 1; if (batch[mid] < g + 1) l2 = mid + 1; else h2v = mid; }
        sr[1] = l2;
    }
    __syncthreads();
    int lo = sr[0], hi = sr[1];
    int cs = (hi - lo + PPARTS - 1) / PPARTS;
    int start = lo + part * cs;
    int end = start + cs < hi ? start + cs : hi;
    int cg = threadIdx.x & 3;       // 4 channel-groups of 8 channels (uint4)
    int slot = threadIdx.x >> 2;    // 64 node slots
    float a[8] = {0.f, 0.f, 0.f, 0.f, 0.f, 0.f, 0.f, 0.f};
    for (int n = start + slot; n < end; n += 64) {
        uint4 v = *(const uint4*)(x2buf + (size_t)n * 32 + cg * 8);
        a[0] += bfl(v.x); a[1] += bfh(v.x);
        a[2] += bfl(v.y); a[3] += bfh(v.y);
        a[4] += bfl(v.z); a[5] += bfh(v.z);
        a[6] += bfl(v.w); a[7] += bfh(v.w);
    }
    __shared__ float red[256][8];
    #pragma unroll
    for (int k = 0; k < 8; ++k) red[threadIdx.x][k] = a[k];
    __syncthreads();
    #pragma unroll
    for (int o = 128; o >= 4; o >>= 1) {
        if (threadIdx.x < o) {
            #pragma unroll
            for (int k = 0; k < 8; ++k)
                red[threadIdx.x][k] += red[threadIdx.x + o][k];
        }
        __syncthreads();
    }
    if (threadIdx.x < 4) {
        float* dst = partial + (size_t)(g * PPARTS + part) * 32 + threadIdx.x * 8;
        #pragma unroll
        for (int k = 0; k < 8; ++k) dst[k] = red[threadIdx.x][k];
    }
}

// ---------------- pooling stage 2 + head: one block per graph ----------------
__global__ void k_head(const float* __restrict__ partial, const int* __restrict__ batch,
                       const float* __restrict__ lin_w, const float* __restrict__ lin_b,
                       float* __restrict__ out, int N) {
    int g = blockIdx.x;
    int t = threadIdx.x;            // 64 threads
    int ch = t & 31;
    int half = t >> 5;
    float acc = 0.f;
    for (int p = half * (PPARTS / 2); p < (half + 1) * (PPARTS / 2); ++p)
        acc += partial[(size_t)(g * PPARTS + p) * 32 + ch];
    acc += __shfl_xor(acc, 32, 64);
    int lo = 0, hi = N;
    while (lo < hi) { int mid = (lo + hi) >> 1; if (batch[mid] < g) lo = mid + 1; else hi = mid; }
    int l2 = lo, h2v = N;
    while (l2 < h2v) { int mid = (l2 + h2v) >> 1; if (batch[mid] < g + 1) l2 = mid + 1; else h2v = mid; }
    float c = fmaxf((float)(h2v - lo), 1.0f);
    float v = acc / c * lin_w[ch];
    #pragma unroll
    for (int o = 16; o; o >>= 1) v += __shfl_xor(v, o, 32);
    if (t == 0) out[g] = 1.0f / (1.0f + __expf(-(v + lin_b[0])));
}

extern "C" void kernel_launch(void* const* d_in, const int* in_sizes, int n_in,
                              void* d_out, int out_size, void* d_ws, size_t ws_size,
                              hipStream_t stream) {
    const float* x     = (const float*)d_in[0];
    const int*   ei    = (const int*)d_in[1];
    const int*   batch = (const int*)d_in[2];
    const float* W1    = (const float*)d_in[4];
    const float* a1s   = (const float*)d_in[5];
    const float* a1d   = (const float*)d_in[6];
    const float* b1    = (const float*)d_in[7];
    const float* W2    = (const float*)d_in[8];
    const float* a2s   = (const float*)d_in[9];
    const float* a2d   = (const float*)d_in[10];
    const float* b2    = (const float*)d_in[11];
    const float* lin_w = (const float*)d_in[12];
    const float* lin_b = (const float*)d_in[13];
    float* out = (float*)d_out;

    int N = in_sizes[0];
    int E = in_sizes[1] / 2;
    int ET = E + N;
    int G = out_size;
    int nb = (N + 127) >> 7;        // dst-buckets of 128 nodes
    int nblk = (ET + 8191) / 8192;

    char* ws = (char*)d_ws;
    size_t off = 0;
    auto alloc = [&](size_t bytes) -> char* {
        char* p = ws + off;
        off = (off + bytes + 255) & ~(size_t)255;
        return p;
    };
    int*   cursor  = (int*)alloc(1024 * 4);
    int*   pairbuf = (int*)alloc((size_t)nb * BCAP * 4);
    int*   rowp    = (int*)alloc((size_t)N * 4);
    int*   degarr  = (int*)alloc((size_t)N * 4);
    int*   col     = (int*)alloc((size_t)nb * BCAP * 4);
    float* S       = (float*)alloc((size_t)N * 16);
    unsigned int* h2f8 = (unsigned int*)alloc((size_t)N * 32);
    float* es2     = (float*)alloc((size_t)N * 4);
    float* ed2     = (float*)alloc((size_t)N * 4);
    float* dots    = (float*)alloc(32);
    unsigned short* x2buf = (unsigned short*)alloc((size_t)N * 64);
    float* partial = (float*)alloc((size_t)G * PPARTS * 32 * 4);

    k_init<<<1, 1024, 0, stream>>>(cursor, nb, W1, a1s, a1d, dots);
    k_scat<<<nblk, 1024, 0, stream>>>(ei, cursor, pairbuf, E, N, nb);
    k_build<<<nb, 512, 0, stream>>>(pairbuf, cursor, rowp, degarr, col, x, dots, S, N);
    k_h2<<<(N + 255) / 256, 256, 0, stream>>>(S, W1, b1, W2, a2s, a2d, h2f8, es2, ed2, N);
    k_agg<<<((size_t)N * 8 + 255) / 256, 256, 0, stream>>>(h2f8, es2, ed2, rowp, degarr, col, b2, x2buf, N);
    k_psum<<<G * PPARTS, 256, 0, stream>>>(x2buf, batch, partial, N);
    k_head<<<G, 64, 0, stream>>>(partial, batch, lin_w, lin_b, out, N);
}